// Round 4
// baseline (537.294 us; speedup 1.0000x reference)
//
#include <hip/hip_runtime.h>
#include <hip/hip_bf16.h>
#include <cstdint>

#define BB 64
#define TT 2048
#define FD 256
#define UU 32

#if defined(__has_builtin)
#  if __has_builtin(__builtin_amdgcn_permlane16_swap) && __has_builtin(__builtin_amdgcn_permlane32_swap)
#    define HAVE_PLSWAP 1
#  endif
#endif
#ifndef HAVE_PLSWAP
#  define HAVE_PLSWAP 0
#endif

// ---------------------------------------------------------------------------
// Kernel 1: pot[b,t,u] = dot(x[b,t,:], K[:,u]) + bias[u] (+ boundaries)
// (unchanged, verified at 532 us baseline)
// ---------------------------------------------------------------------------
__global__ __launch_bounds__(64) void potentials_kernel(
    const float* __restrict__ x, const float* __restrict__ K,
    const float* __restrict__ bias, const float* __restrict__ lb,
    const float* __restrict__ rb, float* __restrict__ pot)
{
    __shared__ __align__(16) float lds[16384];   // 64 KB total
    float* xs = lds;            // [32 rows][256 f], swizzled quads
    float* Kt = lds + 8192;     // [32 u]  [256 f], swizzled quads

    const int tid = threadIdx.x;
    const int ug = tid & 7;
    const int rg = tid >> 3;

    for (int j = 0; j < 128; ++j) {
        const int e = j * 64 + tid;
        const int f = e >> 5;
        const int u = e & 31;
        Kt[u * 256 + (((f >> 2) ^ (u & 7)) << 2) + (f & 3)] = K[e];
    }

    float bu[4], lu4[4], ru4[4];
    #pragma unroll
    for (int m = 0; m < 4; ++m) {
        bu[m]  = bias[ug + 8 * m];
        lu4[m] = lb[ug + 8 * m];
        ru4[m] = rb[ug + 8 * m];
    }

    const int tiles = (BB * TT) / 32;     // 4096
    for (int tile = blockIdx.x; tile < tiles; tile += gridDim.x) {
        const int row0 = tile * 32;
        __syncthreads();
        #pragma unroll 4
        for (int k = 0; k < 32; ++k) {
            const float4 v = *(const float4*)(x + (size_t)(row0 + k) * FD + tid * 4);
            *(float4*)&xs[k * 256 + ((tid ^ (k & 7)) << 2)] = v;
        }
        __syncthreads();

        float acc[4][4];
        #pragma unroll
        for (int i = 0; i < 4; ++i)
            #pragma unroll
            for (int m = 0; m < 4; ++m) acc[i][m] = 0.f;

        #pragma unroll 4
        for (int q = 0; q < 64; ++q) {
            float4 xq[4], kq[4];
            #pragma unroll
            for (int i = 0; i < 4; ++i)
                xq[i] = *(const float4*)&xs[(rg + 8 * i) * 256 + ((q ^ rg) << 2)];
            #pragma unroll
            for (int m = 0; m < 4; ++m)
                kq[m] = *(const float4*)&Kt[(ug + 8 * m) * 256 + ((q ^ ug) << 2)];
            #pragma unroll
            for (int i = 0; i < 4; ++i)
                #pragma unroll
                for (int m = 0; m < 4; ++m) {
                    acc[i][m] += xq[i].x * kq[m].x;
                    acc[i][m] += xq[i].y * kq[m].y;
                    acc[i][m] += xq[i].z * kq[m].z;
                    acc[i][m] += xq[i].w * kq[m].w;
                }
        }

        #pragma unroll
        for (int i = 0; i < 4; ++i) {
            const int row = row0 + rg + 8 * i;
            const int t = row & (TT - 1);
            #pragma unroll
            for (int m = 0; m < 4; ++m) {
                pot[(size_t)row * UU + ug + 8 * m] =
                    acc[i][m] + bu[m] + (t == 0 ? lu4[m] : 0.f)
                              + (t == TT - 1 ? ru4[m] : 0.f);
            }
        }
    }
}

// ---------------------------------------------------------------------------
// Cross-lane helpers. DPP via builtin (HW-verified: baseline v1 used 0xB1).
// permlane swaps via BUILTINS, not inline asm: v_permlane*_swap_b32 has
// mandatory VALU wait-states on gfx950; the hazard recognizer inserts them
// for builtins but NOT around opaque inline-asm blobs (the v2/v3 failure).
// ---------------------------------------------------------------------------
template<int CTRL>
__device__ __forceinline__ float dppf(float v) {
    return __int_as_float(__builtin_amdgcn_update_dpp(
        __float_as_int(v), __float_as_int(v), CTRL, 0xF, 0xF, true));
}

// returns fmax(own, partner^32) — exact merge of the two 32-lane halves
__device__ __forceinline__ float pl32max(float v) {
#if HAVE_PLSWAP
    auto r = __builtin_amdgcn_permlane32_swap(__float_as_uint(v), __float_as_uint(v),
                                              false, false);
    return fmaxf(__uint_as_float(r[0]), __uint_as_float(r[1]));
#else
    return fmaxf(v, __shfl_xor(v, 32, 64));
#endif
}

// returns v[lane^16]; xA selects which output slot carries it (probe-derived)
__device__ __forceinline__ float pl16x(float v, bool xA) {
#if HAVE_PLSWAP
    auto r = __builtin_amdgcn_permlane16_swap(__float_as_uint(v), __float_as_uint(v),
                                              false, false);
    return xA ? __uint_as_float(r[0]) : __uint_as_float(r[1]);
#else
    (void)xA; return __shfl_xor(v, 16, 64);
#endif
}

template<bool B> struct BoolC { static constexpr bool v = B; };

// ---------------------------------------------------------------------------
// Kernel 2: values-only serial forward, v4.
// Layout: u = lane&31 (output tag), h = lane>>5 (k-half), p = lane&15.
// Each lane reduces k in [16h,16h+16) for output u; halves merged with
// pl32max; rows 0,3 (bit4==bit5) keep their own mm, rows 1,2 need
// mm[lane^16] (pl16x); 16-lane row all-gather via DPP XOR-butterfly with
// cc[] pre-permuted by p^m. All primitives are runtime-probed; any
// deviation drops the wave to a known-good LDS-broadcast loop.
// Arithmetic bit-identical to baseline (same rounded adds, exact max
// reassociation, single-rounded +pot) -> chk matches exactly.
// ---------------------------------------------------------------------------
__global__ __launch_bounds__(64) void vit_values_kernel(
    const float* __restrict__ pot, const float* __restrict__ chain,
    float* __restrict__ chk)
{
    __shared__ float mbuf[32];             // safe-path broadcast buffer

    const int lane = threadIdx.x;
    const int u = lane & 31;
    const int h = lane >> 5;
    const int p = lane & 15;
    const int b = blockIdx.x;
    const float* pb = pot + (size_t)b * TT * UU;

    // rows 0,3 keep their own mm
    const bool own = (((lane >> 4) & 1) == h);

    auto butterfly = [&](float V, float (&d)[16]) {
        d[0]  = V;
        d[1]  = dppf<0xB1>(V);       // quad_perm [1,0,3,2] : p^1
        d[2]  = dppf<0x4E>(V);       // quad_perm [2,3,0,1] : p^2
        d[3]  = dppf<0x1B>(V);       // quad_perm [3,2,1,0] : p^3
        d[7]  = dppf<0x141>(V);      // ROW_HALF_MIRROR     : p^7
        d[6]  = dppf<0x141>(d[1]);   // p^6
        d[5]  = dppf<0x141>(d[2]);   // p^5
        d[4]  = dppf<0x141>(d[3]);   // p^4
        d[15] = dppf<0x140>(V);      // ROW_MIRROR          : p^15
        d[14] = dppf<0x140>(d[1]);   // p^14
        d[13] = dppf<0x140>(d[2]);   // p^13
        d[12] = dppf<0x140>(d[3]);   // p^12
        d[11] = dppf<0x140>(d[4]);   // p^11
        d[10] = dppf<0x140>(d[5]);   // p^10
        d[9]  = dppf<0x140>(d[6]);   // p^9
        d[8]  = dppf<0x140>(d[7]);   // p^8
    };

    // ---- runtime probes (once, outside the 2047-step loop) ----
    bool xA = false, ok16, ok32, bfok;
#if HAVE_PLSWAP
    {
        auto r = __builtin_amdgcn_permlane16_swap((unsigned)lane, (unsigned)lane,
                                                  false, false);
        xA = ((int)r[0] == (lane ^ 16));
        const bool xB = ((int)r[1] == (lane ^ 16));
        ok16 = (__all((xA || xB) ? 1 : 0) != 0);
    }
    {
        // two-sided probe: +lane catches "both=own", -lane catches "both=partner"
        const bool e1 = (pl32max((float)lane)  == (float)(lane | 32));
        const bool e2 = (pl32max(-(float)lane) == -(float)(lane & 31));
        ok32 = (__all((e1 && e2) ? 1 : 0) != 0);
    }
#else
    ok16 = true; ok32 = true;      // helpers are shfl_xor -> always correct
#endif
    {
        float W = (float)(p * 5 + 7);
        float tb[16];
        butterfly(W, tb);
        bool ok = true;
        #pragma unroll
        for (int m = 0; m < 16; ++m)
            ok = ok && (tb[m] == (float)((p ^ m) * 5 + 7));
        bfok = (__all(ok ? 1 : 0) != 0);
    }
    const bool fastok = ok16 && ok32 && bfok;   // wave-uniform

    float cc[16], s[16];
    #pragma unroll
    for (int m = 0; m < 16; ++m) {
        const int k = 16 * h + (p ^ m);
        cc[m] = chain[k * UU + u];
        s[m]  = pb[k];                       // state at t=0 = pot[:,0,:]
    }

    auto run = [&](auto FC) {
        constexpr bool FAST = decltype(FC)::v;

        auto step = [&](float potv, int t) {
            float a[16];
            #pragma unroll
            for (int m = 0; m < 16; ++m) a[m] = s[m] + cc[m];
            // max3-shaped exact reduction (depth 3, 8 ops)
            const float r0 = fmaxf(fmaxf(a[0],  a[1]),  a[2]);
            const float r1 = fmaxf(fmaxf(a[3],  a[4]),  a[5]);
            const float r2 = fmaxf(fmaxf(a[6],  a[7]),  a[8]);
            const float r3 = fmaxf(fmaxf(a[9],  a[10]), a[11]);
            const float r4 = fmaxf(fmaxf(a[12], a[13]), a[14]);
            const float r5 = fmaxf(fmaxf(r0, r1), r2);
            const float r6 = fmaxf(fmaxf(r3, r4), a[15]);
            const float pm = fmaxf(r5, r6);

            float mx;
            if constexpr (FAST) mx = pl32max(pm);
            else                mx = fmaxf(pm, __shfl_xor(pm, 32, 64));
            const float mm = mx + potv;      // exact max, single rounding

            if (h == 0 && (t & 63) == 63)
                chk[((size_t)b * 33 + ((t >> 6) + 1)) * UU + u] = mm;

            if constexpr (FAST) {
                const float X = pl16x(mm, xA);      // mm[lane^16]
                const float V = own ? mm : X;       // V[p] = s_new[16h + p]
                butterfly(V, s);
            } else {
                mbuf[u] = mm;                       // both h-lanes, same value
                #pragma unroll
                for (int m = 0; m < 16; ++m) s[m] = mbuf[16 * h + (p ^ m)];
            }
        };

        float pr[8], pn[8];
        #pragma unroll
        for (int j = 0; j < 8; ++j) pr[j] = pb[(1 + j) * UU + u];

        #pragma unroll 1
        for (int g = 0; g < 255; ++g) {
            #pragma unroll
            for (int j = 0; j < 8; ++j) {
                int tp = 9 + 8 * g + j;
                if (tp > TT - 1) tp = TT - 1;
                pn[j] = pb[tp * UU + u];
            }
            const int t0 = 1 + 8 * g;
            #pragma unroll
            for (int j = 0; j < 8; ++j)
                step(pr[j], t0 + j);
            #pragma unroll
            for (int j = 0; j < 8; ++j) pr[j] = pn[j];
        }
        // tail: t = 2041..2047 (final checkpoint wck = 32 at t = 2047)
        #pragma unroll
        for (int j = 0; j < 7; ++j)
            step(pr[j], 2041 + j);
    };

    if (fastok) run(BoolC<true>{});
    else        run(BoolC<false>{});
}

// ---------------------------------------------------------------------------
// Kernel 3: parallel window recompute (unchanged, verified).
// ---------------------------------------------------------------------------
__global__ __launch_bounds__(64) void vit_window_kernel(
    const float* __restrict__ pot, const float* __restrict__ chain,
    const float* __restrict__ chk, unsigned char* __restrict__ Mg,
    unsigned char* __restrict__ bpg)
{
    __shared__ float potL[64 * 32];   // 8 KB: pot rows 64w .. 64w+63
    __shared__ float mbuf[32];

    const int lane = threadIdx.x;
    const int u = lane & 31;
    const int h = lane >> 5;
    const int hbase = 16 * h;
    const int w = blockIdx.x;
    const int b = blockIdx.y;
    const float* pb = pot + (size_t)b * TT * UU;
    const int r0 = 64 * w;

    {
        const float4* src = (const float4*)(pb + (size_t)r0 * UU);
        float4* dst = (float4*)potL;
        #pragma unroll
        for (int k = 0; k < 8; ++k) dst[lane + 64 * k] = src[lane + 64 * k];
    }
    __syncthreads();

    float cc[16];
    #pragma unroll
    for (int i = 0; i < 16; ++i) cc[i] = chain[(hbase + i) * UU + u];

    float s[16];
    if (w == 0) {
        #pragma unroll
        for (int i = 0; i < 16; ++i) s[i] = potL[hbase + i];          // state t=0
    } else {
        #pragma unroll
        for (int i = 0; i < 16; ++i) s[i] = chk[((size_t)b * 33 + w) * UU + hbase + i];
    }

    int orig = u;
    unsigned char* bb = bpg + (size_t)b * (TT - 1) * UU;

    const int tl0 = (w == 0) ? 1 : 0;
    #pragma unroll 1
    for (int tl = tl0; tl < 64; ++tl) {
        const int t = r0 + tl;
        const float potv = potL[tl * UU + u];

        float a[16];
        #pragma unroll
        for (int i = 0; i < 16; ++i) a[i] = s[i] + cc[i];

        // first-occurrence argmax: pairwise tree, right wins only if strictly >
        float v8[8]; int i8[8];
        #pragma unroll
        for (int i = 0; i < 8; ++i) {
            const bool c = a[2*i+1] > a[2*i];
            v8[i] = c ? a[2*i+1] : a[2*i];
            i8[i] = c ? (2*i+1) : (2*i);
        }
        float v4[4]; int i4[4];
        #pragma unroll
        for (int i = 0; i < 4; ++i) {
            const bool c = v8[2*i+1] > v8[2*i];
            v4[i] = c ? v8[2*i+1] : v8[2*i];
            i4[i] = c ? i8[2*i+1] : i8[2*i];
        }
        float v2[2]; int i2[2];
        #pragma unroll
        for (int i = 0; i < 2; ++i) {
            const bool c = v4[2*i+1] > v4[2*i];
            v2[i] = c ? v4[2*i+1] : v4[2*i];
            i2[i] = c ? i4[2*i+1] : i4[2*i];
        }
        const bool cf = v2[1] > v2[0];
        const float pv = cf ? v2[1] : v2[0];
        const int pidx = hbase + (cf ? i2[1] : i2[0]);

        const float opv = __shfl_xor(pv, 32, 64);
        const int   opi = __shfl_xor(pidx, 32, 64);
        const bool take = h ? (opv >= pv) : (opv > pv);   // tie -> lower half
        const int  mv   = take ? opi : pidx;
        const float mm  = fmaxf(pv, opv) + potv;

        if (h == 0) bb[(size_t)(t - 1) * UU + u] = (unsigned char)mv;
        orig = __shfl(orig, mv, 64);

        mbuf[u] = mm;
        const float4 x0 = *(const float4*)&mbuf[hbase + 0];
        const float4 x1 = *(const float4*)&mbuf[hbase + 4];
        const float4 x2 = *(const float4*)&mbuf[hbase + 8];
        const float4 x3 = *(const float4*)&mbuf[hbase + 12];
        s[0]=x0.x; s[1]=x0.y; s[2]=x0.z;  s[3]=x0.w;
        s[4]=x1.x; s[5]=x1.y; s[6]=x1.z;  s[7]=x1.w;
        s[8]=x2.x; s[9]=x2.y; s[10]=x2.z; s[11]=x2.w;
        s[12]=x3.x; s[13]=x3.y; s[14]=x3.z; s[15]=x3.w;
    }

    if (h == 0) Mg[(size_t)b * 1024 + w * UU + u] = (unsigned char)orig;
}

// ---------------------------------------------------------------------------
// Kernel 4: per-batch backtrack (unchanged, verified).
// ---------------------------------------------------------------------------
__global__ __launch_bounds__(64) void vit_backtrack_kernel(
    const float* __restrict__ chk, const unsigned char* __restrict__ Mg,
    const unsigned char* __restrict__ bpg, int* __restrict__ out)
{
    __shared__ __align__(16) unsigned char bp[(TT - 1) * UU];   // 65504 B

    const int lane = threadIdx.x;
    const int b = blockIdx.x;
    const unsigned char* bb = bpg + (size_t)b * (TT - 1) * UU;

    // stage bp: 4094 int4s
    #pragma unroll 4
    for (int i = 0; i < 64; ++i) {
        const int idx = i * 64 + lane;
        if (idx < 4094)
            ((int4*)bp)[idx] = ((const int4*)bb)[idx];
    }

    // last_tag = argmax_u chk[b][32][u], smallest u on tie
    float fv = (lane < 32) ? chk[((size_t)b * 33 + 32) * UU + lane] : -INFINITY;
    int fi = lane & 31;
    #pragma unroll
    for (int mask = 16; mask >= 1; mask >>= 1) {
        const float ov = __shfl_xor(fv, mask, 64);
        const int oi = __shfl_xor(fi, mask, 64);
        if (ov > fv || (ov == fv && oi < fi)) { fv = ov; fi = oi; }
    }
    int bt = __shfl(fi, 0, 64);

    // boundary walk over Mg (uniform addresses -> broadcast global loads)
    int my_btag = 0;
    #pragma unroll 1
    for (int w = 31; w >= 0; --w) {
        if (lane == w) my_btag = bt;         // tag at t = 64w+63
        bt = Mg[(size_t)b * 1024 + w * 32 + bt];
    }

    __syncthreads();                         // bp staging visible

    if (lane < 32) {
        const int w = lane;
        int tag = my_btag;
        int t = w * 64 + 63;
        int* ob = out + (size_t)b * TT;
        ob[t] = tag;
        #pragma unroll 1
        for (; t >= w * 64 + 1; --t) {
            tag = bp[(t - 1) * UU + tag];
            ob[t - 1] = tag;
        }
    }
}

// ---------------------------------------------------------------------------
extern "C" void kernel_launch(void* const* d_in, const int* in_sizes, int n_in,
                              void* d_out, int out_size, void* d_ws, size_t ws_size,
                              hipStream_t stream)
{
    const float* x     = (const float*)d_in[0];
    const float* K     = (const float*)d_in[1];
    const float* bias  = (const float*)d_in[2];
    const float* chain = (const float*)d_in[3];
    const float* lb    = (const float*)d_in[4];
    const float* rb    = (const float*)d_in[5];
    int* out = (int*)d_out;

    float* pot = (float*)d_ws;                          // 16 MB
    float* chk = pot + (size_t)BB * TT * UU;            // 64*33*32 floats = 264 KB
    unsigned char* Mg  = (unsigned char*)(chk + (size_t)BB * 33 * UU);  // 64 KB
    unsigned char* bpg = Mg + (size_t)BB * 32 * UU;     // 64*2047*32 = 4 MB

    potentials_kernel<<<512, 64, 0, stream>>>(x, K, bias, lb, rb, pot);
    vit_values_kernel<<<BB, 64, 0, stream>>>(pot, chain, chk);
    vit_window_kernel<<<dim3(32, BB), 64, 0, stream>>>(pot, chain, chk, Mg, bpg);
    vit_backtrack_kernel<<<BB, 64, 0, stream>>>(chk, Mg, bpg, out);
}